// Round 10
// baseline (241.690 us; speedup 1.0000x reference)
//
#include <hip/hip_runtime.h>
#include <hip/hip_bf16.h>

#define BB 4
#define TT 2048
#define CC 1024
#define HH 16
#define DD 64
#define MM (BB*TT)   // 8192 rows

typedef unsigned short u16;
typedef __bf16 bf16x8 __attribute__((ext_vector_type(8)));
typedef __bf16 bf16x4v __attribute__((ext_vector_type(4)));
typedef u16 u16x8 __attribute__((ext_vector_type(8)));
typedef u16 u16x4 __attribute__((ext_vector_type(4)));
typedef float f32x4 __attribute__((ext_vector_type(4)));

__device__ __forceinline__ u16 f2bf(float f) {
  union { float f; unsigned u; } v; v.f = f;
  unsigned u = v.u;
  return (u16)((u + 0x7fffu + ((u >> 16) & 1u)) >> 16);  // RNE
}
__device__ __forceinline__ float bf2f(u16 s) {
  union { unsigned u; float f; } v; v.u = ((unsigned)s) << 16; return v.f;
}
__device__ __forceinline__ bf16x8 ld_bf16x8(const u16* p) {
  return *reinterpret_cast<const bf16x8*>(p);
}
__device__ __forceinline__ f32x4 zero4() {
  f32x4 z; z[0] = 0.f; z[1] = 0.f; z[2] = 0.f; z[3] = 0.f; return z;
}

// async global->LDS DMA, 16 B/lane. LDS dest = wave-uniform base + lane*16.
__device__ __forceinline__ void gld_lds16(const u16* g, u16* l) {
  __builtin_amdgcn_global_load_lds(
      (const __attribute__((address_space(1))) void*)g,
      (__attribute__((address_space(3))) void*)l, 16, 0, 0);
}
// s_waitcnt vmcnt(N) (exp=7, lgkm=15 -> untouched)
__device__ __forceinline__ void wait_vm0() { __builtin_amdgcn_s_waitcnt(0x0F70); }
__device__ __forceinline__ void wait_vm2() { __builtin_amdgcn_s_waitcnt(0x0F72); }

// pull value from lane `srclane` (0..63) of the wave
__device__ __forceinline__ float lane_pull(float x, int srclane) {
  int r = __builtin_amdgcn_ds_bpermute(srclane << 2, __builtin_bit_cast(int, x));
  return __builtin_bit_cast(float, r);
}

// ---------------- merged prep: cast x + transpose-cast both weights ----------------
#define NC4B ((MM * CC / 4) / 256)
__global__ void k_prep(const float* __restrict__ x, u16* __restrict__ xb,
                       const float* __restrict__ Wa, u16* __restrict__ Wab,
                       const float* __restrict__ Wp, u16* __restrict__ Wpb) {
  __shared__ float tile[32][33];
  const int bx = blockIdx.x;
  if (bx < NC4B) {
    int i = bx * 256 + threadIdx.x;
    const float4 v = reinterpret_cast<const float4*>(x)[i];
    u16x4 r; r.x = f2bf(v.x); r.y = f2bf(v.y); r.z = f2bf(v.z); r.w = f2bf(v.w);
    reinterpret_cast<u16x4*>(xb)[i] = r;
    return;
  }
  const float* W; u16* Wt; int K, N, b2;
  if (bx < NC4B + 3072) { W = Wa; Wt = Wab; K = CC; N = 3 * CC; b2 = bx - NC4B; }
  else                  { W = Wp; Wt = Wpb; K = CC; N = CC;     b2 = bx - NC4B - 3072; }
  const int nblk = N / 32;
  const int nb = (b2 % nblk) * 32, kb = (b2 / nblk) * 32;
  const int tx = threadIdx.x & 31, ty = threadIdx.x >> 5;
  #pragma unroll
  for (int i = ty; i < 32; i += 8)
    tile[i][tx] = W[(size_t)(kb + i) * N + nb + tx];
  __syncthreads();
  #pragma unroll
  for (int i = ty; i < 32; i += 8)
    Wt[(size_t)(nb + i) * K + kb + tx] = f2bf(tile[tx][i]);
}

// ---------------- GEMM  C[M,N] = A[M,K](bf16) * Bt[N,K](bf16)^T ----------------
// m97-proven shape: stage(DMA) -> drain -> barrier -> compute -> barrier.
template<int EPI>
__global__ __launch_bounds__(256, 3)
void k_gemm_bt(const u16* __restrict__ A, const u16* __restrict__ Bt,
               float* __restrict__ outF, u16* __restrict__ qb, u16* __restrict__ kb,
               u16* __restrict__ vt, int N, int K)
{
  __shared__ u16 As[128 * 64];
  __shared__ u16 Bs[128 * 64];
  const int tid  = threadIdx.x;
  const int lane = tid & 63, w = tid >> 6;
  const int l16  = lane & 15, quad = lane >> 4;
  const int wr = w >> 1, wc = w & 1;
  const int m0 = blockIdx.y * 128, n0 = blockIdx.x * 128;
  const int lr8 = lane >> 3, lc8 = lane & 7;

  f32x4 acc[4][4];
  #pragma unroll
  for (int i = 0; i < 4; ++i)
    #pragma unroll
    for (int j = 0; j < 4; ++j) acc[i][j] = zero4();

  for (int k0 = 0; k0 < K; k0 += 64) {
    __syncthreads();
    #pragma unroll
    for (int p = 0; p < 4; ++p) {
      const int row = w * 32 + p * 8 + lr8;
      const int cs  = lc8 ^ (row & 7);
      gld_lds16(A  + (size_t)(m0 + row) * K + k0 + cs * 8, &As[(w * 32 + p * 8) * 64]);
      gld_lds16(Bt + (size_t)(n0 + row) * K + k0 + cs * 8, &Bs[(w * 32 + p * 8) * 64]);
    }
    wait_vm0();
    __syncthreads();
    #pragma unroll
    for (int s = 0; s < 2; ++s) {
      bf16x8 af[4], bfr[4];
      #pragma unroll
      for (int i = 0; i < 4; ++i) {
        int mrow = wr * 64 + i * 16 + l16;
        af[i]  = ld_bf16x8(&As[mrow * 64 + ((s * 4 + quad) ^ (l16 & 7)) * 8]);
        int nrow = wc * 64 + i * 16 + l16;
        bfr[i] = ld_bf16x8(&Bs[nrow * 64 + ((s * 4 + quad) ^ (l16 & 7)) * 8]);
      }
      #pragma unroll
      for (int i = 0; i < 4; ++i)
        #pragma unroll
        for (int j = 0; j < 4; ++j)
          acc[i][j] = __builtin_amdgcn_mfma_f32_16x16x32_bf16(af[i], bfr[j], acc[i][j], 0, 0, 0);
    }
  }

  // epilogue: C/D layout col = lane&15, row = quad*4 + reg (m89-verified)
  #pragma unroll
  for (int i = 0; i < 4; ++i) {
    #pragma unroll
    for (int j = 0; j < 4; ++j) {
      const int n = n0 + wc * 64 + j * 16 + l16;
      const int mb = m0 + wr * 64 + i * 16 + quad * 4;   // 4 consecutive m
      if (EPI == 0) {
        #pragma unroll
        for (int r = 0; r < 4; ++r)
          outF[(size_t)(mb + r) * N + n] = acc[i][j][r];
      } else {
        const int b = mb >> 11, tb = mb & 2047;  // t aligned 4, no b-crossing
        if (n < CC) {
          const int h = n >> 6, d = n & 63;
          #pragma unroll
          for (int r = 0; r < 4; ++r)
            qb[(((size_t)(b * HH + h) * TT + tb + r) << 6) + d] = f2bf(acc[i][j][r]);
        } else if (n < 2 * CC) {
          const int n2 = n - CC; const int h = n2 >> 6, d = n2 & 63;
          #pragma unroll
          for (int r = 0; r < 4; ++r)
            kb[(((size_t)(b * HH + h) * TT + tb + r) << 6) + d] = f2bf(acc[i][j][r]);
        } else {
          // v -> [B,H,D,T]: 4 consecutive t at fixed d -> one 8B packed store
          const int n2 = n - 2 * CC; const int h = n2 >> 6, d = n2 & 63;
          u16x4 cv;
          #pragma unroll
          for (int r = 0; r < 4; ++r) cv[r] = f2bf(acc[i][j][r]);
          *reinterpret_cast<u16x4*>(
              vt + ((size_t)(b * HH + h) * DD + d) * TT + tb) = cv;
        }
      }
    }
  }
}

// ---------------- flash attention v9: pipelined 64-k tiles ----------------
// r8 geometry (64x64 K/V tiles, S^T layout, direct exp2) + race-free pipeline:
//  * Ks double-buffered: K(kt+1) DMA issued at iter top, waited one FULL
//    iteration later (top wait_vm0 + barrier) -> latency fully hidden.
//  * Vs single-buffered: V(kt) DMA issued at iter top, waited just before PV
//    with partial vmcnt(2) (K-prefetch stays in flight) -> drain overlaps
//    QK^T + softmax + P-repack.
//  * Every barrier is preceded by an explicit own-wave wait covering exactly
//    what the other waves will read (r3's race class structurally excluded).
// LDS 32 KB -> 5 blocks/CU.
__global__ __launch_bounds__(256, 5)
void k_attn(const u16* __restrict__ qb, const u16* __restrict__ kb,
            const u16* __restrict__ vt, u16* __restrict__ y)
{
  __shared__ u16 Ks[2][64 * 64];
  __shared__ u16 Vs[64 * 64];
  __shared__ u16 QP[64 * 64];   // Q staging (prologue) then P transform (loop)
  const int tid  = threadIdx.x;
  const int lane = tid & 63, w = tid >> 6;
  const int l16  = lane & 15, quad = lane >> 4;
  const int lr8 = lane >> 3, lc8 = lane & 7;

  const int bx = blockIdx.x;
  const int qt = 31 - (bx >> 6);       // heavy q-tiles first
  const int bh = bx & 63;
  const int h  = bh & 15, b = bh >> 4;

  const u16* qptr = qb + ((size_t)bh * TT + qt * 64) * DD;
  const u16* kptr = kb + (size_t)bh * TT * DD;
  const u16* vptr = vt + (size_t)bh * DD * TT;   // [D][T]

  // prologue: kick off K(0) DMA, then stage Q (wave-private) while it flies
  #pragma unroll
  for (int p = 0; p < 2; ++p) {
    const int row = w * 16 + p * 8 + lr8;
    gld_lds16(kptr + (size_t)row * DD + (lc8 ^ lr8) * 8, &Ks[0][(w * 16 + p * 8) * 64]);
  }
  const float qscale = 0.125f * 1.44269504088896340736f;
  #pragma unroll
  for (int p = 0; p < 2; ++p) {
    const int r = w * 16 + p * 8 + lr8;
    u16x8 v = *reinterpret_cast<const u16x8*>(qptr + (size_t)r * DD + lc8 * 8);
    u16x8 o;
    #pragma unroll
    for (int e = 0; e < 8; ++e) o[e] = f2bf(bf2f(v[e]) * qscale);
    *reinterpret_cast<u16x8*>(&QP[r * 64 + (lc8 ^ lr8) * 8]) = o;
  }
  bf16x8 qf[2];
  #pragma unroll
  for (int s = 0; s < 2; ++s)
    qf[s] = ld_bf16x8(&QP[(w * 16 + l16) * 64 + ((s * 4 + quad) ^ (l16 & 7)) * 8]);

  float rsum = 0.f;   // per-lane partial of l for q-row w*16+l16
  f32x4 O[4];
  #pragma unroll
  for (int j = 0; j < 4; ++j) O[j] = zero4();

  const int ktiles = qt + 1;
  for (int kt = 0; kt < ktiles; ++kt) {
    const int buf = kt & 1;
    wait_vm0();          // own K(kt) landed (issued a full iteration ago)
    __syncthreads();     // everyone's K(kt) landed; Vs/Ks[buf^1] free to restage

    // issue V(kt) stage (2 insts), then K(kt+1) prefetch (2 insts)
    #pragma unroll
    for (int p = 0; p < 2; ++p) {
      const int row = w * 16 + p * 8 + lr8;
      gld_lds16(vptr + (size_t)row * TT + kt * 64 + (lc8 ^ lr8) * 8,
                &Vs[(w * 16 + p * 8) * 64]);
    }
    const bool pre = (kt + 1 < ktiles);   // block-uniform
    if (pre) {
      const u16* kt0 = kptr + (size_t)(kt + 1) * 64 * DD;
      #pragma unroll
      for (int p = 0; p < 2; ++p) {
        const int row = w * 16 + p * 8 + lr8;
        gld_lds16(kt0 + (size_t)row * DD + (lc8 ^ lr8) * 8,
                  &Ks[buf ^ 1][(w * 16 + p * 8) * 64]);
      }
    }

    // S^T[k = j*16+quad*4+r][q = l16] on Ks[buf] (resident)
    f32x4 St[4];
    #pragma unroll
    for (int j = 0; j < 4; ++j) St[j] = zero4();
    #pragma unroll
    for (int s = 0; s < 2; ++s) {
      #pragma unroll
      for (int j = 0; j < 4; ++j) {
        bf16x8 kfr = ld_bf16x8(&Ks[buf][(j * 16 + l16) * 64 +
                                        ((s * 4 + quad) ^ (l16 & 7)) * 8]);
        St[j] = __builtin_amdgcn_mfma_f32_16x16x32_bf16(kfr, qf[s], St[j], 0, 0, 0);
      }
    }
    if (kt == qt) {  // diagonal tile: causal mask (local: k > q -> -inf)
      const int qg = w * 16 + l16;
      #pragma unroll
      for (int j = 0; j < 4; ++j)
        #pragma unroll
        for (int r = 0; r < 4; ++r)
          if (j * 16 + quad * 4 + r > qg) St[j][r] = -__builtin_inff();
    }

    // p = 2^S directly (|S| << 120; masked -inf -> 0). l per-lane.
    #pragma unroll
    for (int j = 0; j < 4; ++j)
      #pragma unroll
      for (int r = 0; r < 4; ++r) {
        float p = __builtin_amdgcn_exp2f(St[j][r]);
        St[j][r] = p;
        rsum += p;
      }

    // P repack: lane holds k-contiguous quads of q-row l16 -> b64 writes
    #pragma unroll
    for (int j = 0; j < 4; ++j) {
      union { bf16x4v bv; u16x4 u; } cv;
      cv.bv[0] = (__bf16)St[j][0]; cv.bv[1] = (__bf16)St[j][1];
      cv.bv[2] = (__bf16)St[j][2]; cv.bv[3] = (__bf16)St[j][3];
      const int c = j * 2 + (quad >> 1);
      const int off = w * 1024 + l16 * 64 + ((c ^ (l16 & 7)) << 3) + ((quad & 1) << 2);
      *reinterpret_cast<u16x4*>(&QP[off]) = cv.u;
    }

    // V(kt) must be resident for everyone: partial wait leaves K-prefetch
    // (issued after V) in flight across the barrier.
    if (pre) wait_vm2(); else wait_vm0();
    __syncthreads();

    #pragma unroll
    for (int s = 0; s < 2; ++s) {
      bf16x8 pf = ld_bf16x8(&QP[w * 1024 + l16 * 64 +
                                ((s * 4 + quad) ^ (l16 & 7)) * 8]);
      #pragma unroll
      for (int j = 0; j < 4; ++j) {
        bf16x8 vf = ld_bf16x8(&Vs[(j * 16 + l16) * 64 +
                                  ((s * 4 + quad) ^ (l16 & 7)) * 8]);
        O[j] = __builtin_amdgcn_mfma_f32_16x16x32_bf16(pf, vf, O[j], 0, 0, 0);
      }
    }
  }

  // epilogue: reduce l across the 4 quads holding this q-row, O /= l, write y
  rsum += __shfl_xor(rsum, 16);
  rsum += __shfl_xor(rsum, 32);
  const float linv = 1.0f / rsum;
  f32x4 lv;
  #pragma unroll
  for (int r = 0; r < 4; ++r) lv[r] = lane_pull(linv, quad * 4 + r);
  #pragma unroll
  for (int j = 0; j < 4; ++j) {
    O[j] *= lv;
    #pragma unroll
    for (int r = 0; r < 4; ++r) {
      int t  = qt * 64 + w * 16 + quad * 4 + r;
      int ch = h * 64 + j * 16 + l16;
      y[(size_t)(b * TT + t) * CC + ch] = f2bf(O[j][r]);
    }
  }
}

extern "C" void kernel_launch(void* const* d_in, const int* in_sizes, int n_in,
                              void* d_out, int out_size, void* d_ws, size_t ws_size,
                              hipStream_t stream) {
  const float* x  = (const float*)d_in[0];   // [B,T,C]
  const float* Wa = (const float*)d_in[1];   // [C,3C]
  const float* Wp = (const float*)d_in[2];   // [C,C]
  float* out = (float*)d_out;                // [B,T,C] fp32

  u16* ws   = (u16*)d_ws;
  u16* xb   = ws;                             // M*C
  u16* Wab  = xb   + (size_t)MM * CC;         // 3C*C (W_attn^T)
  u16* Wpb  = Wab  + (size_t)3 * CC * CC;     // C*C  (W_proj^T)
  u16* qbuf = Wpb  + (size_t)CC * CC;         // [B,H,T,D]
  u16* kbuf = qbuf + (size_t)MM * CC;         // [B,H,T,D]
  u16* vtb  = kbuf + (size_t)MM * CC;         // [B,H,D,T]
  u16* yb   = vtb  + (size_t)MM * CC;         // [B,T,C]

  k_prep<<<NC4B + 3072 + 1024, 256, 0, stream>>>(x, xb, Wa, Wab, Wp, Wpb);
  k_gemm_bt<1><<<dim3(3 * CC / 128, MM / 128), 256, 0, stream>>>(
      xb, Wab, nullptr, qbuf, kbuf, vtb, 3 * CC, CC);
  k_attn<<<64 * 32, 256, 0, stream>>>(qbuf, kbuf, vtb, yb);
  k_gemm_bt<0><<<dim3(CC / 128, MM / 128), 256, 0, stream>>>(
      yb, Wpb, out, nullptr, nullptr, nullptr, CC, CC);
}

// Round 11
// 239.871 us; speedup vs baseline: 1.0076x; 1.0076x over previous
//
#include <hip/hip_runtime.h>
#include <hip/hip_bf16.h>

#define BB 4
#define TT 2048
#define CC 1024
#define HH 16
#define DD 64
#define MM (BB*TT)   // 8192 rows

typedef unsigned short u16;
typedef __bf16 bf16x8 __attribute__((ext_vector_type(8)));
typedef __bf16 bf16x4v __attribute__((ext_vector_type(4)));
typedef u16 u16x8 __attribute__((ext_vector_type(8)));
typedef u16 u16x4 __attribute__((ext_vector_type(4)));
typedef float f32x4 __attribute__((ext_vector_type(4)));

__device__ __forceinline__ u16 f2bf(float f) {
  union { float f; unsigned u; } v; v.f = f;
  unsigned u = v.u;
  return (u16)((u + 0x7fffu + ((u >> 16) & 1u)) >> 16);  // RNE
}
__device__ __forceinline__ float bf2f(u16 s) {
  union { unsigned u; float f; } v; v.u = ((unsigned)s) << 16; return v.f;
}
__device__ __forceinline__ bf16x8 ld_bf16x8(const u16* p) {
  return *reinterpret_cast<const bf16x8*>(p);
}
__device__ __forceinline__ f32x4 zero4() {
  f32x4 z; z[0] = 0.f; z[1] = 0.f; z[2] = 0.f; z[3] = 0.f; return z;
}

// async global->LDS DMA, 16 B/lane. LDS dest = wave-uniform base + lane*16.
__device__ __forceinline__ void gld_lds16(const u16* g, u16* l) {
  __builtin_amdgcn_global_load_lds(
      (const __attribute__((address_space(1))) void*)g,
      (__attribute__((address_space(3))) void*)l, 16, 0, 0);
}
// explicit drain of LDS-DMA: s_waitcnt vmcnt(0)
__device__ __forceinline__ void wait_vm0() { __builtin_amdgcn_s_waitcnt(0x0F70); }

// pull value from lane `srclane` (0..63) of the wave
__device__ __forceinline__ float lane_pull(float x, int srclane) {
  int r = __builtin_amdgcn_ds_bpermute(srclane << 2, __builtin_bit_cast(int, x));
  return __builtin_bit_cast(float, r);
}

// ---------------- merged prep: cast x + transpose-cast both weights ----------------
#define NC4B ((MM * CC / 4) / 256)
__global__ void k_prep(const float* __restrict__ x, u16* __restrict__ xb,
                       const float* __restrict__ Wa, u16* __restrict__ Wab,
                       const float* __restrict__ Wp, u16* __restrict__ Wpb) {
  __shared__ float tile[32][33];
  const int bx = blockIdx.x;
  if (bx < NC4B) {
    int i = bx * 256 + threadIdx.x;
    const float4 v = reinterpret_cast<const float4*>(x)[i];
    u16x4 r; r.x = f2bf(v.x); r.y = f2bf(v.y); r.z = f2bf(v.z); r.w = f2bf(v.w);
    reinterpret_cast<u16x4*>(xb)[i] = r;
    return;
  }
  const float* W; u16* Wt; int K, N, b2;
  if (bx < NC4B + 3072) { W = Wa; Wt = Wab; K = CC; N = 3 * CC; b2 = bx - NC4B; }
  else                  { W = Wp; Wt = Wpb; K = CC; N = CC;     b2 = bx - NC4B - 3072; }
  const int nblk = N / 32;
  const int nb = (b2 % nblk) * 32, kb = (b2 / nblk) * 32;
  const int tx = threadIdx.x & 31, ty = threadIdx.x >> 5;
  #pragma unroll
  for (int i = ty; i < 32; i += 8)
    tile[i][tx] = W[(size_t)(kb + i) * N + nb + tx];
  __syncthreads();
  #pragma unroll
  for (int i = ty; i < 32; i += 8)
    Wt[(size_t)(nb + i) * K + kb + tx] = f2bf(tile[tx][i]);
}

// ---------------- GEMM  C[M,N] = A[M,K](bf16) * Bt[N,K](bf16)^T ----------------
// m97-proven shape: stage(DMA) -> drain -> barrier -> compute -> barrier.
// (256,4): r10 counters show 64 arch + 64 acc = 128 unified regs — exactly the
// 4-waves/SIMD budget. Occupancy cap 28%->50% for more barrier-drain overlap.
template<int EPI>
__global__ __launch_bounds__(256, 4)
void k_gemm_bt(const u16* __restrict__ A, const u16* __restrict__ Bt,
               float* __restrict__ outF, u16* __restrict__ qb, u16* __restrict__ kb,
               u16* __restrict__ vt, int N, int K)
{
  __shared__ u16 As[128 * 64];
  __shared__ u16 Bs[128 * 64];
  const int tid  = threadIdx.x;
  const int lane = tid & 63, w = tid >> 6;
  const int l16  = lane & 15, quad = lane >> 4;
  const int wr = w >> 1, wc = w & 1;
  const int m0 = blockIdx.y * 128, n0 = blockIdx.x * 128;
  const int lr8 = lane >> 3, lc8 = lane & 7;

  f32x4 acc[4][4];
  #pragma unroll
  for (int i = 0; i < 4; ++i)
    #pragma unroll
    for (int j = 0; j < 4; ++j) acc[i][j] = zero4();

  for (int k0 = 0; k0 < K; k0 += 64) {
    __syncthreads();
    #pragma unroll
    for (int p = 0; p < 4; ++p) {
      const int row = w * 32 + p * 8 + lr8;
      const int cs  = lc8 ^ (row & 7);
      gld_lds16(A  + (size_t)(m0 + row) * K + k0 + cs * 8, &As[(w * 32 + p * 8) * 64]);
      gld_lds16(Bt + (size_t)(n0 + row) * K + k0 + cs * 8, &Bs[(w * 32 + p * 8) * 64]);
    }
    wait_vm0();
    __syncthreads();
    #pragma unroll
    for (int s = 0; s < 2; ++s) {
      bf16x8 af[4], bfr[4];
      #pragma unroll
      for (int i = 0; i < 4; ++i) {
        int mrow = wr * 64 + i * 16 + l16;
        af[i]  = ld_bf16x8(&As[mrow * 64 + ((s * 4 + quad) ^ (l16 & 7)) * 8]);
        int nrow = wc * 64 + i * 16 + l16;
        bfr[i] = ld_bf16x8(&Bs[nrow * 64 + ((s * 4 + quad) ^ (l16 & 7)) * 8]);
      }
      #pragma unroll
      for (int i = 0; i < 4; ++i)
        #pragma unroll
        for (int j = 0; j < 4; ++j)
          acc[i][j] = __builtin_amdgcn_mfma_f32_16x16x32_bf16(af[i], bfr[j], acc[i][j], 0, 0, 0);
    }
  }

  // epilogue: C/D layout col = lane&15, row = quad*4 + reg (m89-verified)
  #pragma unroll
  for (int i = 0; i < 4; ++i) {
    #pragma unroll
    for (int j = 0; j < 4; ++j) {
      const int n = n0 + wc * 64 + j * 16 + l16;
      const int mb = m0 + wr * 64 + i * 16 + quad * 4;   // 4 consecutive m
      if (EPI == 0) {
        #pragma unroll
        for (int r = 0; r < 4; ++r)
          outF[(size_t)(mb + r) * N + n] = acc[i][j][r];
      } else {
        const int b = mb >> 11, tb = mb & 2047;  // t aligned 4, no b-crossing
        if (n < CC) {
          const int h = n >> 6, d = n & 63;
          #pragma unroll
          for (int r = 0; r < 4; ++r)
            qb[(((size_t)(b * HH + h) * TT + tb + r) << 6) + d] = f2bf(acc[i][j][r]);
        } else if (n < 2 * CC) {
          const int n2 = n - CC; const int h = n2 >> 6, d = n2 & 63;
          #pragma unroll
          for (int r = 0; r < 4; ++r)
            kb[(((size_t)(b * HH + h) * TT + tb + r) << 6) + d] = f2bf(acc[i][j][r]);
        } else {
          // v -> [B,H,D,T]: 4 consecutive t at fixed d -> one 8B packed store
          const int n2 = n - 2 * CC; const int h = n2 >> 6, d = n2 & 63;
          u16x4 cv;
          #pragma unroll
          for (int r = 0; r < 4; ++r) cv[r] = f2bf(acc[i][j][r]);
          *reinterpret_cast<u16x4*>(
              vt + ((size_t)(b * HH + h) * DD + d) * TT + tb) = cv;
        }
      }
    }
  }
}

// ---------------- flash attention (r8-exact: the measured plateau) ----------------
// S^T layout, direct exp2 (no online softmax), two-barrier DMA staging,
// 64x64 tiles, 24 KB LDS -> 6 blocks/CU. r9 (128-k) and r10 (pipelined) both
// regressed vs this shape: occupancy trades dominate barrier-count trades.
__global__ __launch_bounds__(256, 6)
void k_attn(const u16* __restrict__ qb, const u16* __restrict__ kb,
            const u16* __restrict__ vt, u16* __restrict__ y)
{
  __shared__ u16 Ks[64 * 64];
  __shared__ u16 Vs[64 * 64];
  __shared__ u16 QP[64 * 64];   // Q staging (prologue) then P transform (loop)
  const int tid  = threadIdx.x;
  const int lane = tid & 63, w = tid >> 6;
  const int l16  = lane & 15, quad = lane >> 4;
  const int lr8 = lane >> 3, lc8 = lane & 7;

  const int bx = blockIdx.x;
  const int qt = 31 - (bx >> 6);       // heavy q-tiles first
  const int bh = bx & 63;
  const int h  = bh & 15, b = bh >> 4;

  const u16* qptr = qb + ((size_t)bh * TT + qt * 64) * DD;
  const u16* kptr = kb + (size_t)bh * TT * DD;
  const u16* vptr = vt + (size_t)bh * DD * TT;   // [D][T]

  // Q: wave-private staging (rows w*16..+16) + frag read; prescale by
  // 1/sqrt(D)*log2(e) -> scores in log2 domain.
  const float qscale = 0.125f * 1.44269504088896340736f;
  #pragma unroll
  for (int p = 0; p < 2; ++p) {
    const int r = w * 16 + p * 8 + lr8;
    u16x8 v = *reinterpret_cast<const u16x8*>(qptr + (size_t)r * DD + lc8 * 8);
    u16x8 o;
    #pragma unroll
    for (int e = 0; e < 8; ++e) o[e] = f2bf(bf2f(v[e]) * qscale);
    *reinterpret_cast<u16x8*>(&QP[r * 64 + (lc8 ^ lr8) * 8]) = o;
  }
  bf16x8 qf[2];
  #pragma unroll
  for (int s = 0; s < 2; ++s)
    qf[s] = ld_bf16x8(&QP[(w * 16 + l16) * 64 + ((s * 4 + quad) ^ (l16 & 7)) * 8]);

  float rsum = 0.f;   // per-lane partial of l for q-row w*16+l16
  f32x4 O[4];
  #pragma unroll
  for (int j = 0; j < 4; ++j) O[j] = zero4();

  const int ktiles = qt + 1;
  for (int kt = 0; kt < ktiles; ++kt) {
    __syncthreads();   // all prior-tile frag reads complete before restaging
    {
      const u16* kt0 = kptr + (size_t)kt * 64 * DD;
      const u16* vt0 = vptr + kt * 64;
      #pragma unroll
      for (int p = 0; p < 2; ++p) {
        const int row = w * 16 + p * 8 + lr8;
        const int cs  = lc8 ^ lr8;
        gld_lds16(kt0 + (size_t)row * DD + cs * 8, &Ks[(w * 16 + p * 8) * 64]);
        gld_lds16(vt0 + (size_t)row * TT + cs * 8, &Vs[(w * 16 + p * 8) * 64]);
      }
    }
    wait_vm0();          // own DMA landed
    __syncthreads();     // everyone's DMA landed

    // S^T[k = j*16+quad*4+r][q = l16] : A = K-frag, B = Q-frag (same layouts)
    f32x4 St[4];
    #pragma unroll
    for (int j = 0; j < 4; ++j) St[j] = zero4();
    #pragma unroll
    for (int s = 0; s < 2; ++s) {
      #pragma unroll
      for (int j = 0; j < 4; ++j) {
        bf16x8 kfr = ld_bf16x8(&Ks[(j * 16 + l16) * 64 + ((s * 4 + quad) ^ (l16 & 7)) * 8]);
        St[j] = __builtin_amdgcn_mfma_f32_16x16x32_bf16(kfr, qf[s], St[j], 0, 0, 0);
      }
    }
    if (kt == qt) {  // diagonal tile: causal mask (local: k > q -> -inf)
      const int qg = w * 16 + l16;
      #pragma unroll
      for (int j = 0; j < 4; ++j)
        #pragma unroll
        for (int r = 0; r < 4; ++r)
          if (j * 16 + quad * 4 + r > qg) St[j][r] = -__builtin_inff();
    }

    // p = 2^S directly (|S| << 120; masked -inf -> 0). l per-lane.
    #pragma unroll
    for (int j = 0; j < 4; ++j)
      #pragma unroll
      for (int r = 0; r < 4; ++r) {
        float p = __builtin_amdgcn_exp2f(St[j][r]);
        St[j][r] = p;
        rsum += p;
      }

    // P repack: lane holds k-contiguous quads of q-row l16 -> b64 writes
    #pragma unroll
    for (int j = 0; j < 4; ++j) {
      union { bf16x4v bv; u16x4 u; } cv;
      cv.bv[0] = (__bf16)St[j][0]; cv.bv[1] = (__bf16)St[j][1];
      cv.bv[2] = (__bf16)St[j][2]; cv.bv[3] = (__bf16)St[j][3];
      const int c = j * 2 + (quad >> 1);               // 16B chunk of k-granule
      const int off = w * 1024 + l16 * 64 + ((c ^ (l16 & 7)) << 3) + ((quad & 1) << 2);
      *reinterpret_cast<u16x4*>(&QP[off]) = cv.u;
    }
    #pragma unroll
    for (int s = 0; s < 2; ++s) {
      bf16x8 pf = ld_bf16x8(&QP[w * 1024 + l16 * 64 + ((s * 4 + quad) ^ (l16 & 7)) * 8]);
      #pragma unroll
      for (int j = 0; j < 4; ++j) {
        bf16x8 vf = ld_bf16x8(&Vs[(j * 16 + l16) * 64 + ((s * 4 + quad) ^ (l16 & 7)) * 8]);
        O[j] = __builtin_amdgcn_mfma_f32_16x16x32_bf16(pf, vf, O[j], 0, 0, 0);
      }
    }
  }

  // epilogue: reduce l across the 4 quads holding this q-row, O /= l, write y
  rsum += __shfl_xor(rsum, 16);
  rsum += __shfl_xor(rsum, 32);
  const float linv = 1.0f / rsum;
  f32x4 lv;
  #pragma unroll
  for (int r = 0; r < 4; ++r) lv[r] = lane_pull(linv, quad * 4 + r);
  #pragma unroll
  for (int j = 0; j < 4; ++j) {
    O[j] *= lv;
    #pragma unroll
    for (int r = 0; r < 4; ++r) {
      int t  = qt * 64 + w * 16 + quad * 4 + r;
      int ch = h * 64 + j * 16 + l16;
      y[(size_t)(b * TT + t) * CC + ch] = f2bf(O[j][r]);
    }
  }
}

extern "C" void kernel_launch(void* const* d_in, const int* in_sizes, int n_in,
                              void* d_out, int out_size, void* d_ws, size_t ws_size,
                              hipStream_t stream) {
  const float* x  = (const float*)d_in[0];   // [B,T,C]
  const float* Wa = (const float*)d_in[1];   // [C,3C]
  const float* Wp = (const float*)d_in[2];   // [C,C]
  float* out = (float*)d_out;                // [B,T,C] fp32

  u16* ws   = (u16*)d_ws;
  u16* xb   = ws;                             // M*C
  u16* Wab  = xb   + (size_t)MM * CC;         // 3C*C (W_attn^T)
  u16* Wpb  = Wab  + (size_t)3 * CC * CC;     // C*C  (W_proj^T)
  u16* qbuf = Wpb  + (size_t)CC * CC;         // [B,H,T,D]
  u16* kbuf = qbuf + (size_t)MM * CC;         // [B,H,T,D]
  u16* vtb  = kbuf + (size_t)MM * CC;         // [B,H,D,T]
  u16* yb   = vtb  + (size_t)MM * CC;         // [B,T,C]

  k_prep<<<NC4B + 3072 + 1024, 256, 0, stream>>>(x, xb, Wa, Wab, Wp, Wpb);
  k_gemm_bt<1><<<dim3(3 * CC / 128, MM / 128), 256, 0, stream>>>(
      xb, Wab, nullptr, qbuf, kbuf, vtb, 3 * CC, CC);
  k_attn<<<64 * 32, 256, 0, stream>>>(qbuf, kbuf, vtb, yb);
  k_gemm_bt<0><<<dim3(CC / 128, MM / 128), 256, 0, stream>>>(
      yb, Wpb, out, nullptr, nullptr, nullptr, CC, CC);
}